// Round 7
// baseline (291.349 us; speedup 1.0000x reference)
//
#include <hip/hip_runtime.h>
#include <math.h>

#define B_TOT 2048
#define R_TOT 512
#define D_TOT 256
#define LOG2E 1.4426950408889634f
#define SCALE_C 2.220446049250313e-16f   // 2^-52 exact

typedef float vf4 __attribute__((ext_vector_type(4)));
typedef float vf2 __attribute__((ext_vector_type(2)));

// gated = (1 + m1*e)/(1 + e),  e = exp2(A*x + Bc)
// A = -log2e*kappa*tanh(sign), Bc = -A*th, m1 = 1 - sigmoid(mask)
// Ms carries 2^-52 at d%8==0 so each 8-d rcp group's num/den share the same
// scale (ratio exact; den in [2^-52, 2^57], num >= 0.88^8 * 2^-52 -> safe).

// lane^1 swap via DPP quad_perm [1,0,3,2] = 0xB1 (pure VALU, no LDS)
static __device__ __forceinline__ float pair_swap(float v) {
    int i = __builtin_amdgcn_mov_dpp(__float_as_int(v), 0xB1, 0xF, 0xF, true);
    return __int_as_float(i);
}
static __device__ __forceinline__ vf4 exp2v(vf4 t) {
    vf4 e;
    e.x = __builtin_amdgcn_exp2f(t.x);
    e.y = __builtin_amdgcn_exp2f(t.y);
    e.z = __builtin_amdgcn_exp2f(t.z);
    e.w = __builtin_amdgcn_exp2f(t.w);
    return e;
}
static __device__ __forceinline__ vf4 rcpv(vf4 t) {
    vf4 e;
    e.x = __builtin_amdgcn_rcpf(t.x);
    e.y = __builtin_amdgcn_rcpf(t.y);
    e.z = __builtin_amdgcn_rcpf(t.z);
    e.w = __builtin_amdgcn_rcpf(t.w);
    return e;
}

// ---------------------------------------------------------------------------
// Single fused kernel. WG = 256 = 4 waves; wave -> 1 rule; lane l owns
// d = 4l..4l+3. Params computed ONCE per wave into 12 VGPRs (prep fused).
// Each WG processes 8 batch-groups of 16 batches -> grid (128,16) = 2048 WGs
// = exactly 8 WGs/CU = 32 waves/CU, fully resident, no WG churn: this is the
// round-7 lever (round 6 showed 35% occupancy from 16K tiny WGs was the
// idle source). Per b: 1 coalesced dwordx4 (L2-hit), packed fp32 math,
// 4 exp2 + 1 rcp per 256 elems (sum-model floor 110 cy).
// ---------------------------------------------------------------------------
__global__ __launch_bounds__(256, 8) void main_kernel(
        const float* __restrict__ x,       // [B_TOT][D_TOT]
        const float* __restrict__ th,      // [R_TOT][D_TOT]
        const float* __restrict__ sp,      // [R_TOT][D_TOT]
        const float* __restrict__ ml,      // [R_TOT][D_TOT]
        const float* __restrict__ lk,      // [1]
        const float* __restrict__ head_w,  // [R_TOT]
        const float* __restrict__ head_b,  // [1]
        float*       __restrict__ y) {     // [B_TOT]
    __shared__ float rbuf[4][16][36];      // per-wave private; pad 36
    __shared__ float wz[4][16];

    const int tid  = threadIdx.x;
    const int lane = tid & 63;
    const int wave = tid >> 6;
    const int r0   = (blockIdx.x << 2) + wave;   // this wave's rule
    const int bgg0 = blockIdx.y << 3;            // first of 8 batch-groups

    // ---- params: computed once, live in VGPRs for the whole kernel ----
    const float kmul = -LOG2E * __builtin_amdgcn_exp2f(lk[0] * LOG2E);
    const size_t pidx = (size_t)r0 * 64 + lane;  // vf4 index into [R][D]
    const vf4 one = {1.0f, 1.0f, 1.0f, 1.0f};
    vf4 u   = ((const vf4*)sp)[pidx];
    vf4 eu  = exp2v((2.0f * LOG2E) * u);
    vf4 tt  = one - 2.0f * rcpv(eu + one);       // tanh(u)
    vf4 A   = kmul * tt;
    vf4 Bc  = (-A) * ((const vf4*)th)[pidx];
    vf4 em  = exp2v(LOG2E * ((const vf4*)ml)[pidx]);
    vf4 Ms  = rcpv(one + em);                    // m1 = 1 - sigmoid(ml)
    const float kx = (lane & 1) ? 1.0f : SCALE_C;
    Ms.x *= kx;
    const vf4 K = {kx, 1.0f, 1.0f, 1.0f};
    const float w_r = head_w[r0];

    for (int g = 0; g < 8; g++) {
        const int b0 = (bgg0 + g) << 4;
        const vf4* xv = (const vf4*)x + (size_t)b0 * 64 + lane;

        float r8[16];
        #pragma unroll
        for (int b = 0; b < 16; b++) {
            vf4 xb = xv[b * 64];             // coalesced, L2-resident
            vf4 t  = A * xb + Bc;            // v_pk_fma_f32
            vf4 e  = exp2v(t);
            vf4 n  = Ms * e + K;             // scaled numerator factors
            vf4 dd = e * K + K;              // scaled denominator factors
            vf2 hn = n.lo * n.hi;
            vf2 hd = dd.lo * dd.hi;
            float np = hn.x * hn.y;          // lane's 4-d num product
            float dp = hd.x * hd.y;
            float np8 = np * pair_swap(np);  // 8-d group (lane pair)
            float dp8 = dp * pair_swap(dp);
            r8[b] = np8 * __builtin_amdgcn_rcpf(dp8);
        }

        // ---- end-phase: rbuf is wave-private (write+read same wave) ----
        if (!(lane & 1)) {
            #pragma unroll
            for (int b = 0; b < 16; b++)
                rbuf[wave][b][lane >> 1] = r8[b];
        }
        if (lane < 16) {
            const float* rb = &rbuf[wave][lane][0];
            vf4 a0 = *(const vf4*)(rb)      * *(const vf4*)(rb + 4);
            vf4 a1 = *(const vf4*)(rb + 8)  * *(const vf4*)(rb + 12);
            vf4 a2 = *(const vf4*)(rb + 16) * *(const vf4*)(rb + 20);
            vf4 a3 = *(const vf4*)(rb + 24) * *(const vf4*)(rb + 28);
            vf4 m  = (a0 * a1) * (a2 * a3);
            vf2 h  = m.lo * m.hi;
            wz[wave][lane] = w_r * (h.x * h.y);   // w[r0] * z(b,r0)
        }
        __syncthreads();                      // wz visible to wave 0
        if (wave == 0 && lane < 16) {
            float s = wz[0][lane] + wz[1][lane] + wz[2][lane] + wz[3][lane];
            if (blockIdx.x == 0) s += head_b[0];  // bias once per batch
            atomicAdd(&y[b0 + lane], s);
        }
        __syncthreads();                      // protect wz for next g
    }
}

extern "C" void kernel_launch(void* const* d_in, const int* in_sizes, int n_in,
                              void* d_out, int out_size, void* d_ws, size_t ws_size,
                              hipStream_t stream) {
    const float* x  = (const float*)d_in[0];
    const float* th = (const float*)d_in[1];
    const float* sp = (const float*)d_in[2];
    const float* ml = (const float*)d_in[3];
    const float* lk = (const float*)d_in[4];
    const float* hw = (const float*)d_in[5];
    const float* hb = (const float*)d_in[6];
    float* y = (float*)d_out;

    hipMemsetAsync(y, 0, (size_t)out_size * sizeof(float), stream);
    dim3 grid(R_TOT / 4, B_TOT / 128, 1);   // (128, 16) = 2048 WGs = 8/CU
    main_kernel<<<grid, 256, 0, stream>>>(x, th, sp, ml, lk, hw, hb, y);
}

// Round 8
// 135.929 us; speedup vs baseline: 2.1434x; 2.1434x over previous
//
#include <hip/hip_runtime.h>
#include <math.h>

#define B_TOT 2048
#define R_TOT 512
#define D_TOT 256
#define LOG2E 1.4426950408889634f
#define SCALE_C 2.220446049250313e-16f   // 2^-52 exact

typedef float vf4 __attribute__((ext_vector_type(4)));
typedef float vf2 __attribute__((ext_vector_type(2)));

// gated = (1 + m1*e)/(1 + e),  e = exp2(A*x + Bc)
// A = -log2e*kappa*tanh(sign), Bc = -A*th, m1 = 1 - sigmoid(mask)
// Ms carries 2^-52 at d%8==0 so each 8-d rcp group's num/den share the same
// scale (ratio exact, no overflow; proven rounds 5/6/7).

// lane^1 swap via DPP quad_perm [1,0,3,2] = 0xB1 (pure VALU, no LDS)
static __device__ __forceinline__ float pair_swap(float v) {
    int i = __builtin_amdgcn_mov_dpp(__float_as_int(v), 0xB1, 0xF, 0xF, true);
    return __int_as_float(i);
}
static __device__ __forceinline__ vf4 exp2v(vf4 t) {
    vf4 e;
    e.x = __builtin_amdgcn_exp2f(t.x);
    e.y = __builtin_amdgcn_exp2f(t.y);
    e.z = __builtin_amdgcn_exp2f(t.z);
    e.w = __builtin_amdgcn_exp2f(t.w);
    return e;
}
static __device__ __forceinline__ vf4 rcpv(vf4 t) {
    vf4 e;
    e.x = __builtin_amdgcn_rcpf(t.x);
    e.y = __builtin_amdgcn_rcpf(t.y);
    e.z = __builtin_amdgcn_rcpf(t.z);
    e.w = __builtin_amdgcn_rcpf(t.w);
    return e;
}

// ---------------------------------------------------------------------------
// Round 8 = round-5 body (56 VGPR, no spill at (256,4)) + round-7 grid
// (2048 long-lived WGs = 8/CU, no churn) + ZERO barriers (per-wave atomic
// epilogue instead of cross-wave LDS reduce; waves fully decoupled).
// NOTE: __launch_bounds__ second arg must stay 4 — (256,8) empirically caps
// VGPRs at 32 and spills this body to scratch (rounds 4 & 7, 3-10x slower).
// wave -> 1 rule; lane l owns d=4l..4l+3; params in 12 VGPRs for the whole
// kernel; per batch: 1 coalesced dwordx4 (L2-hit), packed fp32, 4 exp2 +
// 1 rcp per 256 elems.
// ---------------------------------------------------------------------------
__global__ __launch_bounds__(256, 4) void main_kernel(
        const float* __restrict__ x,       // [B_TOT][D_TOT]
        const float* __restrict__ th,      // [R_TOT][D_TOT]
        const float* __restrict__ sp,      // [R_TOT][D_TOT]
        const float* __restrict__ ml,      // [R_TOT][D_TOT]
        const float* __restrict__ lk,      // [1]
        const float* __restrict__ head_w,  // [R_TOT]
        const float* __restrict__ head_b,  // [1]
        float*       __restrict__ y) {     // [B_TOT]
    __shared__ float rbuf[4][16][36];      // wave-private transpose buffer

    const int tid  = threadIdx.x;
    const int lane = tid & 63;
    const int wave = tid >> 6;
    const int r0   = (blockIdx.x << 2) + wave;   // this wave's rule
    const int bgg0 = blockIdx.y << 3;            // first of 8 batch-groups

    // ---- params: computed once, live in VGPRs for the whole kernel ----
    const float kmul = -LOG2E * __builtin_amdgcn_exp2f(lk[0] * LOG2E);
    const size_t pidx = (size_t)r0 * 64 + lane;  // vf4 index into [R][D]
    const vf4 one = {1.0f, 1.0f, 1.0f, 1.0f};
    vf4 u   = ((const vf4*)sp)[pidx];
    vf4 eu  = exp2v((2.0f * LOG2E) * u);
    vf4 tt  = one - 2.0f * rcpv(eu + one);       // tanh(u)
    vf4 A   = kmul * tt;
    vf4 Bc  = (-A) * ((const vf4*)th)[pidx];
    vf4 em  = exp2v(LOG2E * ((const vf4*)ml)[pidx]);
    vf4 Ms  = rcpv(one + em);                    // m1 = 1 - sigmoid(ml)
    const float kx = (lane & 1) ? 1.0f : SCALE_C;
    Ms.x *= kx;
    const vf4 K = {kx, 1.0f, 1.0f, 1.0f};
    const float w_r  = head_w[r0];
    const float bias = (blockIdx.x == 0 && wave == 0) ? head_b[0] : 0.0f;

    for (int g = 0; g < 8; g++) {
        const int b0 = (bgg0 + g) << 4;
        const vf4* xv = (const vf4*)x + (size_t)b0 * 64 + lane;

        float r8[16];
        #pragma unroll
        for (int b = 0; b < 16; b++) {
            vf4 xb = xv[b * 64];             // coalesced, L2-resident
            vf4 t  = A * xb + Bc;            // v_pk_fma_f32
            vf4 e  = exp2v(t);
            vf4 n  = Ms * e + K;             // scaled numerator factors
            vf4 dd = e * K + K;              // scaled denominator factors
            vf2 hn = n.lo * n.hi;
            vf2 hd = dd.lo * dd.hi;
            float np = hn.x * hn.y;          // lane's 4-d num product
            float dp = hd.x * hd.y;
            float np8 = np * pair_swap(np);  // 8-d group (lane pair)
            float dp8 = dp * pair_swap(dp);
            r8[b] = np8 * __builtin_amdgcn_rcpf(dp8);
        }

        // ---- wave-private LDS transpose (no barrier needed) ----
        if (!(lane & 1)) {
            #pragma unroll
            for (int b = 0; b < 16; b++)
                rbuf[wave][b][lane >> 1] = r8[b];
        }
        if (lane < 16) {
            const float* rb = &rbuf[wave][lane][0];
            vf4 a0 = *(const vf4*)(rb)      * *(const vf4*)(rb + 4);
            vf4 a1 = *(const vf4*)(rb + 8)  * *(const vf4*)(rb + 12);
            vf4 a2 = *(const vf4*)(rb + 16) * *(const vf4*)(rb + 20);
            vf4 a3 = *(const vf4*)(rb + 24) * *(const vf4*)(rb + 28);
            vf4 m  = (a0 * a1) * (a2 * a3);
            vf2 h  = m.lo * m.hi;
            float z = h.x * h.y;             // z(b0+lane, r0)
            atomicAdd(&y[b0 + lane], fmaf(w_r, z, bias));
        }
    }
}

extern "C" void kernel_launch(void* const* d_in, const int* in_sizes, int n_in,
                              void* d_out, int out_size, void* d_ws, size_t ws_size,
                              hipStream_t stream) {
    const float* x  = (const float*)d_in[0];
    const float* th = (const float*)d_in[1];
    const float* sp = (const float*)d_in[2];
    const float* ml = (const float*)d_in[3];
    const float* lk = (const float*)d_in[4];
    const float* hw = (const float*)d_in[5];
    const float* hb = (const float*)d_in[6];
    float* y = (float*)d_out;

    hipMemsetAsync(y, 0, (size_t)out_size * sizeof(float), stream);
    dim3 grid(R_TOT / 4, B_TOT / 128, 1);   // (128, 16) = 2048 WGs = 8/CU
    main_kernel<<<grid, 256, 0, stream>>>(x, th, sp, ml, lk, hw, hb, y);
}

// Round 9
// 132.805 us; speedup vs baseline: 2.1938x; 1.0235x over previous
//
#include <hip/hip_runtime.h>
#include <math.h>

#define B_TOT 2048
#define R_TOT 512
#define D_TOT 256
#define LOG2E 1.4426950408889634f
#define NPLANE (R_TOT * D_TOT)

typedef float vf4 __attribute__((ext_vector_type(4)));
typedef float vf2 __attribute__((ext_vector_type(2)));

// gated = (1 + m1*e)/(1 + e),  e = exp2(A*x + Bc)
// A = -log2e*kappa*tanh(sign), Bc = -A*th, m1 = 1 - sigmoid(mask)
// 4-wide num/den per lane: den <= (1+2^21)^4 ~ 2^84 — no scaling needed.

__global__ void prep_kernel(const float* __restrict__ th,
                            const float* __restrict__ sp,
                            const float* __restrict__ ml,
                            const float* __restrict__ lk,
                            float* __restrict__ pp) {
    int idx = blockIdx.x * 256 + threadIdx.x;   // r*256 + d
    if (idx >= NPLANE) return;
    float kmul = -LOG2E * __builtin_amdgcn_exp2f(lk[0] * LOG2E);
    float u  = sp[idx];
    float eu = __builtin_amdgcn_exp2f(2.0f * LOG2E * u);
    float t  = 1.0f - 2.0f * __builtin_amdgcn_rcpf(eu + 1.0f);
    float A  = kmul * t;
    float Bc = -A * th[idx];
    float em = __builtin_amdgcn_exp2f(LOG2E * ml[idx]);
    float m1 = __builtin_amdgcn_rcpf(1.0f + em);
    pp[idx]              = A;
    pp[NPLANE + idx]     = Bc;
    pp[2 * NPLANE + idx] = m1;
}

// DPP cross-lane: xor1 = quad_perm [1,0,3,2] = 0xB1; xor2 = [2,3,0,1] = 0x4E
static __device__ __forceinline__ float dpp_xor1(float v) {
    int i = __builtin_amdgcn_mov_dpp(__float_as_int(v), 0xB1, 0xF, 0xF, true);
    return __int_as_float(i);
}
static __device__ __forceinline__ float dpp_xor2(float v) {
    int i = __builtin_amdgcn_mov_dpp(__float_as_int(v), 0x4E, 0xF, 0xF, true);
    return __int_as_float(i);
}
static __device__ __forceinline__ vf4 exp2v(vf4 t) {
    vf4 e;
    e.x = __builtin_amdgcn_exp2f(t.x);
    e.y = __builtin_amdgcn_exp2f(t.y);
    e.z = __builtin_amdgcn_exp2f(t.z);
    e.w = __builtin_amdgcn_exp2f(t.w);
    return e;
}

// ---------------------------------------------------------------------------
// Round 9: wave owns 4 RULES x 4 BATCHES per 16-batch group.
//  - complete 4-rule partial per batch in-wave -> 1 atomic/(WG,batch),
//    262K total (round-8's 1.05M per-wave atomics caused vmem backpressure)
//  - ZERO __syncthreads (no vmcnt(0) barrier drain)
//  - 4x in-register x reuse; next group's 4 loads prefetched, pinned by
//    sched_barrier(0) so the scheduler can't re-sink them (round-6 failure)
//  - __launch_bounds__(256,4): (256,8) caps VGPR at 32 and spills (r4/r7!)
// grid (128,16) = 2048 WGs = 8/CU, long-lived, no churn.
// ---------------------------------------------------------------------------
__global__ __launch_bounds__(256, 4) void main_kernel(
        const float* __restrict__ x,       // [B_TOT][D_TOT]
        const float* __restrict__ pp,      // 3 planes of [R_TOT][D_TOT]
        const float* __restrict__ head_w,  // [R_TOT]
        const float* __restrict__ head_b,  // [1]
        float*       __restrict__ y) {     // [B_TOT]
    __shared__ float rbuf[4][16][36];      // wave-private; rows 16B-aligned

    const int tid   = threadIdx.x;
    const int lane  = tid & 63;
    const int wave  = tid >> 6;
    const int rbase = blockIdx.x << 2;     // 4 rules per WG (shared by waves)
    const int bgg0  = blockIdx.y << 3;     // 8 groups of 16 batches

    // ---- params: 12 vf4 in VGPRs for the whole kernel ----
    vf4 A[4], Bc[4], Ms[4];
    #pragma unroll
    for (int j = 0; j < 4; j++) {
        size_t pidx = (size_t)(rbase + j) * 64 + lane;
        A[j]  = ((const vf4*)pp)[pidx];
        Bc[j] = ((const vf4*)(pp + NPLANE))[pidx];
        Ms[j] = ((const vf4*)(pp + 2 * NPLANE))[pidx];
    }
    const vf4 one = {1.0f, 1.0f, 1.0f, 1.0f};
    // per-lane head weight for the end-phase (lane&3 selects the rule)
    float w0 = head_w[rbase], w1 = head_w[rbase + 1];
    float w2 = head_w[rbase + 2], w3 = head_w[rbase + 3];
    int lj = lane & 3;
    float wsel = (lj == 0) ? w0 : ((lj == 1) ? w1 : ((lj == 2) ? w2 : w3));
    const float bias = (blockIdx.x == 0) ? head_b[0] : 0.0f;

    // x base for this wave's 4 batch rows; row stride 64 vf4, group 1024 vf4
    const vf4* xbase = (const vf4*)x
                       + ((size_t)(bgg0 * 16 + (wave << 2))) * 64 + lane;

    vf4 cur[4], nxt[4];
    #pragma unroll
    for (int i = 0; i < 4; i++) cur[i] = xbase[i * 64];

    #pragma unroll 1
    for (int g = 0; g < 8; g++) {
        // ---- prefetch next group's 4 rows (pinned before compute) ----
        int gn = (g < 7) ? g + 1 : 7;
        #pragma unroll
        for (int i = 0; i < 4; i++) nxt[i] = xbase[gn * 1024 + i * 64];
        __builtin_amdgcn_sched_barrier(0);

        // ---- 16 rows: (batch i, rule j) ----
        #pragma unroll
        for (int i = 0; i < 4; i++) {
            vf4 xb = cur[i];
            #pragma unroll
            for (int j = 0; j < 4; j++) {
                vf4 t  = A[j] * xb + Bc[j];     // v_pk_fma_f32
                vf4 e  = exp2v(t);
                vf4 n  = Ms[j] * e + one;       // numerator factors
                vf4 dd = e + one;               // denominator factors
                vf2 hn = n.lo * n.hi;
                vf2 hd = dd.lo * dd.hi;
                float np = hn.x * hn.y;
                float dp = hd.x * hd.y;
                float r4 = np * __builtin_amdgcn_rcpf(dp);  // 4-d ratio <= 1
                float r8 = r4 * dpp_xor1(r4);   // 8-d (lane-pair) ratio
                if (!(lane & 1))
                    rbuf[wave][i * 4 + j][lane >> 1] = r8;
            }
        }

        // ---- end-phase (wave-private, no barrier): row l = (b=l>>2, r=l&3)
        if (lane < 16) {
            const float* rb = &rbuf[wave][lane][0];
            vf4 a0 = *(const vf4*)(rb)      * *(const vf4*)(rb + 4);
            vf4 a1 = *(const vf4*)(rb + 8)  * *(const vf4*)(rb + 12);
            vf4 a2 = *(const vf4*)(rb + 16) * *(const vf4*)(rb + 20);
            vf4 a3 = *(const vf4*)(rb + 24) * *(const vf4*)(rb + 28);
            vf4 m  = (a0 * a1) * (a2 * a3);
            vf2 h  = m.lo * m.hi;
            float z  = h.x * h.y;               // z(batch, rule)
            float t  = wsel * z;                // w[r] * z
            float t1 = t + dpp_xor1(t);         // sum over rule pairs
            float t2 = t1 + dpp_xor2(t1);       // full 4-rule sum at lane 4i
            if ((lane & 3) == 0) {
                int b = ((bgg0 + g) << 4) + (wave << 2) + (lane >> 2);
                atomicAdd(&y[b], t2 + bias);    // bias once: only rx==0 WGs
            }
        }

        #pragma unroll
        for (int i = 0; i < 4; i++) cur[i] = nxt[i];
    }
}

extern "C" void kernel_launch(void* const* d_in, const int* in_sizes, int n_in,
                              void* d_out, int out_size, void* d_ws, size_t ws_size,
                              hipStream_t stream) {
    const float* x  = (const float*)d_in[0];
    const float* th = (const float*)d_in[1];
    const float* sp = (const float*)d_in[2];
    const float* ml = (const float*)d_in[3];
    const float* lk = (const float*)d_in[4];
    const float* hw = (const float*)d_in[5];
    const float* hb = (const float*)d_in[6];
    float* y = (float*)d_out;

    float* pp = (float*)d_ws;   // 3 * 512 * 256 floats = 1.5 MB

    hipMemsetAsync(y, 0, (size_t)out_size * sizeof(float), stream);
    prep_kernel<<<NPLANE / 256, 256, 0, stream>>>(th, sp, ml, lk, pp);
    dim3 grid(R_TOT / 4, B_TOT / 128, 1);   // (128, 16) = 2048 WGs = 8/CU
    main_kernel<<<grid, 256, 0, stream>>>(x, pp, hw, hb, y);
}